// Round 10
// baseline (472.700 us; speedup 1.0000x reference)
//
#include <hip/hip_runtime.h>

typedef _Float16 half8 __attribute__((ext_vector_type(8)));
typedef float floatx4 __attribute__((ext_vector_type(4)));

#define LBF 2304   // Lb == Lf
#define K1  1152
#define LDK2 2304  // worst-case compacted stride (Kc can be up to 2304)

__device__ __forceinline__ void gll16(const _Float16* g, _Float16* l) {
    __builtin_amdgcn_global_load_lds((const __attribute__((address_space(1))) void*)g,
                                     (__attribute__((address_space(3))) void*)l, 16, 0, 0);
}

// decode Kc from signed pos'[2303] (excl-scan encoding: valid->e, masked->-e-1)
__device__ __forceinline__ int dec_kc(int s) { return (s >= 0) ? s + 1 : -s - 1; }

// ---------------- stage ds (blocks 0..9215) + mask scan (block 9216) ----------
__global__ void stage_scan(const float* __restrict__ f, const float* __restrict__ bsrc,
                           const float* __restrict__ mask,
                           float* __restrict__ ds, int* __restrict__ pos) {
    int tid = threadIdx.x;
    if (blockIdx.x < 9216) {
        long flat = (long)blockIdx.x * 256 + tid;   // [0, 2*4*128*2304)
        int p = flat % 2304;
        long rest = flat / 2304;
        int c = rest % 128;
        int b = (rest / 128) % 4;
        int t = rest / (128 * 4);
        int pi = p / 48, pj = p % 48;
        const float* src = t ? bsrc : f;
        ds[flat] = src[(((long)b * 128 + c) * 96 + 2 * pi) * 96 + 2 * pj];
        return;
    }
    // ---- scan block: mask -> signed compaction index pos' ----
    int mmb[9], loc[9]; int s = 0;
#pragma unroll
    for (int t = 0; t < 9; t++) {
        int p = tid * 9 + t;
        int pi = p / 48, pj = p % 48;
        float sm = 0.f;
#pragma unroll
        for (int u = 0; u < 3; u++)
#pragma unroll
            for (int v = 0; v < 3; v++) {
                int y = pi - 1 + u, x = pj - 1 + v;
                if ((unsigned)y < 48u && (unsigned)x < 48u)
                    sm += mask[(8 * y) * 384 + 8 * x];
            }
        int m = (sm == 0.f) ? 1 : 0;
        mmb[t] = m; loc[t] = s; s += m;
    }
    __shared__ int sh[256];
    sh[tid] = s; __syncthreads();
    for (int off = 1; off < 256; off <<= 1) {
        int v = (tid >= off) ? sh[tid - off] : 0;
        __syncthreads();
        sh[tid] += v;
        __syncthreads();
    }
    int excl = sh[tid] - s;
#pragma unroll
    for (int t = 0; t < 9; t++) {
        int e = excl + loc[t];
        pos[tid * 9 + t] = mmb[t] ? e : (-e - 1);
    }
}

// ---------------- prep: fp patches (x<9) + wn normalized patches (x==9) -------
__global__ void prep_fpwn(const float* __restrict__ ds, _Float16* __restrict__ fp,
                          _Float16* __restrict__ wn) {
    int p = blockIdx.y;                       // [0,2304)
    int b = blockIdx.z;
    int tid = threadIdx.x;                    // 128
    int pi = p / 48, pj = p % 48;
    if (blockIdx.x < 9) {
        int k = blockIdx.x * 128 + tid;       // [0,1152)
        int c = k / 9, r = k % 9, u = r / 3, v = r % 3;
        int y = pi - 1 + u, x = pj - 1 + v;
        float val = 0.f;
        if ((unsigned)y < 48u && (unsigned)x < 48u)
            val = ds[((long)(b * 128 + c)) * 2304 + y * 48 + x];
        fp[((long)b * LBF + p) * K1 + k] = (_Float16)val;
        return;
    }
    // wn role
    const float* dsb = ds + (long)(4 + b) * 128 * 2304;
    float w[9];
    float ss = 0.f;
#pragma unroll
    for (int t = 0; t < 9; t++) {
        int k = tid + t * 128;
        int c = k / 9, r = k % 9, u = r / 3, v = r % 3;
        int y = pi - 1 + u, x = pj - 1 + v;
        float val = 0.f;
        if ((unsigned)y < 48u && (unsigned)x < 48u)
            val = dsb[(long)c * 2304 + y * 48 + x];
        w[t] = val;
        ss += val * val;
    }
    for (int m = 32; m; m >>= 1) ss += __shfl_xor(ss, m);
    __shared__ float sh[2];
    if ((tid & 63) == 0) sh[tid >> 6] = ss;
    __syncthreads();
    float denom = sqrtf(sh[0] + sh[1] + 0.1152f);  // sum(w^2 + ESC)
    float inv = 1.f / denom;
#pragma unroll
    for (int t = 0; t < 9; t++) {
        int k = tid + t * 128;
        wn[((long)b * LBF + p) * K1 + k] = (_Float16)(w[t] * inv);
    }
}

// ---------------- prep: compacted Wt, line-efficient ---------------------------
__global__ void prep_wtc(const float* __restrict__ bsrc, const int* __restrict__ pos,
                         _Float16* __restrict__ wtc) {
    int p = blockIdx.x * 256 + threadIdx.x;   // [0,2304)
    int c = blockIdx.y;                       // [0,128)
    int b = blockIdx.z;
    int sp = pos[p];
    long base = ((long)b * 2048 + c * 16) * LDK2;
    if (sp < 0) {
        int kc = dec_kc(pos[2303]);
        int kp = (kc + 63) & ~63;
        int mo = p + sp + 1;                  // masked ordinal
        if (mo < kp - kc) {
#pragma unroll
            for (int n = 0; n < 16; n++)
                wtc[base + (long)n * LDK2 + kc + mo] = (_Float16)0.f;
        }
        return;
    }
    int pi = p / 48, pj = p % 48;
    const float* src = bsrc + ((long)b * 128 + c) * 96 * 96;
#pragma unroll
    for (int u = 0; u < 4; u++) {
        int y = 2 * pi - 1 + u;
        bool yok = (unsigned)y < 96u;
#pragma unroll
        for (int v = 0; v < 4; v++) {
            int x = 2 * pj - 1 + v;
            float val = 0.f;
            if (yok && (unsigned)x < 96u) val = src[y * 96 + x];
            wtc[base + (long)(u * 4 + v) * LDK2 + sp] = (_Float16)val;
        }
    }
}

// ---------------- NT GEMM, BK=64, double-buffered LDS (R6 winner) -------------
__device__ __forceinline__ void gemm_compute(const _Float16* lA, const _Float16* lB,
                                             floatx4 (&acc)[4][4],
                                             int wr, int wc, int lm, int pcp) {
    half8 af[4], bf[4];
#pragma unroll
    for (int t = 0; t < 4; t++) {
        af[t] = *(const half8*)&lA[(wr * 64 + t * 16 + lm) * 64 + pcp];
        bf[t] = *(const half8*)&lB[(wc * 64 + t * 16 + lm) * 64 + pcp];
    }
#pragma unroll
    for (int i = 0; i < 4; i++)
#pragma unroll
        for (int j = 0; j < 4; j++)
            acc[i][j] = __builtin_amdgcn_mfma_f32_16x16x32_f16(af[i], bf[j], acc[i][j], 0, 0, 0);
#pragma unroll
    for (int t = 0; t < 4; t++) {
        af[t] = *(const half8*)&lA[(wr * 64 + t * 16 + lm) * 64 + (pcp ^ 32)];
        bf[t] = *(const half8*)&lB[(wc * 64 + t * 16 + lm) * 64 + (pcp ^ 32)];
    }
#pragma unroll
    for (int i = 0; i < 4; i++)
#pragma unroll
        for (int j = 0; j < 4; j++)
            acc[i][j] = __builtin_amdgcn_mfma_f32_16x16x32_f16(af[i], bf[j], acc[i][j], 0, 0, 0);
}

__global__ __launch_bounds__(256)
void gemm_nt64(const _Float16* __restrict__ A, const _Float16* __restrict__ B,
               float* __restrict__ C, int M, int N, int ldk, int swapxy,
               const int* __restrict__ Kpos, int Kstat, long sA, long sB, long sC) {
    A += blockIdx.z * sA; B += blockIdx.z * sB; C += blockIdx.z * sC;
    int K;
    if (Kpos) { int kc = dec_kc(Kpos[0]); K = (kc + 63) & ~63; }
    else K = Kstat;
    const int tid = threadIdx.x;
    const int lane = tid & 63, wave = tid >> 6;
    const int wr = wave >> 1, wc = wave & 1;
    const int bm = swapxy ? blockIdx.x : blockIdx.y;
    const int bn = swapxy ? blockIdx.y : blockIdx.x;
    const int m0 = bm * 128, n0 = bn * 128;

    __shared__ _Float16 sm[4][128 * 64];   // [buf*2 + (A=0/B=1)]: 4 x 16 KB

    floatx4 acc[4][4] = {};

    const int lm = lane & 15, q = lane >> 4;
    const int pcp = (q ^ (lm & 7)) * 8;      // substep-0 phys offset (halves)

    const int srow8 = lane >> 3;
    const int gc = ((lane & 7) ^ srow8) * 8;  // global halves offset (XOR swizzle)
    const _Float16* gA[4]; const _Float16* gB[4];
    int dOff[4];
#pragma unroll
    for (int c = 0; c < 4; c++) {
        int r = (wave * 4 + c) * 8 + srow8;
        gA[c] = A + (long)(m0 + r) * ldk + gc;
        gB[c] = B + (long)(n0 + r) * ldk + gc;
        dOff[c] = (wave * 4 + c) * 512;
    }

    if (K > 0) {
#pragma unroll
        for (int c = 0; c < 4; c++) gll16(gA[c], &sm[0][dOff[c]]);
#pragma unroll
        for (int c = 0; c < 4; c++) gll16(gB[c], &sm[1][dOff[c]]);
        __syncthreads();
        int k0 = 0, buf = 0;
        while (true) {
            int kn = k0 + 64;
            if (kn < K) {
                const int nb = (buf ^ 1) * 2;
#pragma unroll
                for (int c = 0; c < 4; c++) gll16(gA[c] + kn, &sm[nb][dOff[c]]);
#pragma unroll
                for (int c = 0; c < 4; c++) gll16(gB[c] + kn, &sm[nb + 1][dOff[c]]);
            }
            gemm_compute(sm[buf * 2], sm[buf * 2 + 1], acc, wr, wc, lm, pcp);
            __syncthreads();
            k0 = kn; buf ^= 1;
            if (k0 >= K) break;
        }
    }

    // C/D layout: col = lane&15, row = (lane>>4)*4 + reg   [m89-verified]
    const int col = n0 + wc * 64 + lm;
    const int rowq = q * 4;
#pragma unroll
    for (int i = 0; i < 4; i++) {
        int row = m0 + wr * 64 + i * 16 + rowq;
#pragma unroll
        for (int j = 0; j < 4; j++)
#pragma unroll
            for (int r = 0; r < 4; r++)
                C[(long)(row + r) * N + col + j * 16] = acc[i][j][r];
    }
}

// ---------------- fused double-diag 9-tap + masked softmax + compaction -------
// out[j][i] = sum_{d2,d1} ST[y0(j,d2)+d1][c(i,d2)+d1] with digit-carry algebra:
// P(P(x)+d2) = x+48*d2, carry: a+d2==48 -> b+1; a+d2==-1 -> 2255+b. Rows are
// block-uniform (9 rows), columns lane-consecutive -> coalesced. FT1 eliminated.
__global__ __launch_bounds__(256)
void fuse_softmax(const float* __restrict__ ST_, const int* __restrict__ pos,
                  _Float16* __restrict__ attTc) {
    int j = blockIdx.x, bb = blockIdx.y;
    int tid = threadIdx.x;
    const float* S = ST_ + (long)bb * LBF * LBF;
    _Float16* orow = attTc + ((long)bb * LBF + j) * LDK2;

    int aj = j / 48, bj = j - aj * 48;
    long rbase[3][3]; bool rok[3][3];
#pragma unroll
    for (int t = 0; t < 3; t++) {
        int d2 = t - 1;
        int ad = aj + d2;
        bool jok; int y0;
        if ((unsigned)ad < 48u) { jok = true;   y0 = j + 48 * d2; }
        else if (ad == 48)      { jok = bj < 47; y0 = bj + 1; }
        else                    { jok = bj > 0;  y0 = 2255 + bj; }
#pragma unroll
        for (int s = 0; s < 3; s++) {
            int y = y0 + s - 1;
            rok[t][s] = jok && (unsigned)y < (unsigned)LBF;
            rbase[t][s] = (long)(rok[t][s] ? y : 0) * LBF;
        }
    }

    float v[9]; int ps[9];
    float mx = -1e30f;
#pragma unroll
    for (int u = 0; u < 9; u++) {
        int x = tid + u * 256;
        int sp = pos[x];
        ps[u] = sp;
        float xv = 0.f;
        if (sp >= 0) {
            int a = x / 48, b = x - a * 48;
            float acc = 0.f;
#pragma unroll
            for (int t = 0; t < 3; t++) {
                int d2 = t - 1;
                int ad = a + d2;
                bool iok; int c;
                if ((unsigned)ad < 48u) { iok = true;   c = x + 48 * d2; }
                else if (ad == 48)      { iok = b < 47; c = b + 1; }
                else                    { iok = b > 0;  c = 2255 + b; }
                if (iok) {
#pragma unroll
                    for (int s = 0; s < 3; s++) {
                        int cc = c + s - 1;
                        if (rok[t][s] && (unsigned)cc < (unsigned)LBF)
                            acc += S[rbase[t][s] + cc];
                    }
                }
            }
            xv = acc * 10.f;
        }
        v[u] = xv;
        mx = fmaxf(mx, xv);
    }
    for (int m = 32; m; m >>= 1) mx = fmaxf(mx, __shfl_xor(mx, m));
    __shared__ float sh[4], sh2[4];
    if ((tid & 63) == 0) sh[tid >> 6] = mx;
    __syncthreads();
    mx = fmaxf(fmaxf(sh[0], sh[1]), fmaxf(sh[2], sh[3]));
    float sum = 0.f;
#pragma unroll
    for (int u = 0; u < 9; u++) { v[u] = __expf(v[u] - mx); sum += v[u]; }
    for (int m = 32; m; m >>= 1) sum += __shfl_xor(sum, m);
    if ((tid & 63) == 0) sh2[tid >> 6] = sum;
    __syncthreads();
    sum = sh2[0] + sh2[1] + sh2[2] + sh2[3];
    float inv = 1.f / sum;
#pragma unroll
    for (int u = 0; u < 9; u++) {
        if (ps[u] >= 0) orow[ps[u]] = (_Float16)(v[u] * inv);
    }
    int kc = dec_kc(pos[2303]);
    int kp = (kc + 63) & ~63;
    if (tid < kp - kc) orow[kc + tid] = (_Float16)0.f;
}

// ---------------- scatter from MT[n][p]: coalesced transposed-conv gather -----
__global__ void scatter_out(const float* __restrict__ MT_, float* __restrict__ out) {
    int yx = blockIdx.x * 256 + threadIdx.x;  // [0, 9216)
    int c = blockIdx.y, b = blockIdx.z;
    int y = yx / 96, x = yx % 96;
    const float* Mb = MT_ + (long)b * 2048 * LBF;
    float s = 0.f;
    for (int uu = (y + 1) & 1; uu < 4; uu += 2) {
        int fi = (y + 1 - uu) >> 1;
        if ((unsigned)fi >= 48u) continue;
        for (int vv = (x + 1) & 1; vv < 4; vv += 2) {
            int fj = (x + 1 - vv) >> 1;
            if ((unsigned)fj >= 48u) continue;
            s += Mb[(long)(c * 16 + uu * 4 + vv) * LBF + fi * 48 + fj];
        }
    }
    out[(((long)b * 128 + c) * 96 + y) * 96 + x] = 0.25f * s;
}

extern "C" void kernel_launch(void* const* d_in, const int* in_sizes, int n_in,
                              void* d_out, int out_size, void* d_ws, size_t ws_size,
                              hipStream_t stream) {
    const float* f    = (const float*)d_in[0];
    const float* bsrc = (const float*)d_in[1];
    const float* mask = (const float*)d_in[2];
    float* out = (float*)d_out;

    char* ws = (char*)d_ws;
    const size_t offR1  = 84934656;
    const size_t offWn  = offR1 + 21233664;
    const size_t offWtc = offR1 + 42467328;
    const size_t offDs  = offWtc + 37748736;          // 165150720 (ds 9.4 MB)
    const size_t offPos = offDs + 2ul * 21233664;     // 207618048
    const size_t NEED   = offPos + 9216;              // 207627264
    if (ws_size < NEED) return;  // visible failure, no OOB writes

    float*    ST    = (float*)(ws + 0);
    float*    MT    = (float*)(ws + 0);
    _Float16* fp    = (_Float16*)(ws + offR1);
    _Float16* wn    = (_Float16*)(ws + offWn);
    _Float16* attTc = (_Float16*)(ws + offR1);
    _Float16* Wtc   = (_Float16*)(ws + offWtc);
    float*    ds    = (float*)(ws + offDs);
    int*      pos   = (int*)(ws + offPos);

    stage_scan<<<dim3(9217), 256, 0, stream>>>(f, bsrc, mask, ds, pos);
    prep_fpwn<<<dim3(10, 2304, 4), 128, 0, stream>>>(ds, fp, wn);
    prep_wtc<<<dim3(9, 128, 4), 256, 0, stream>>>(bsrc, pos, Wtc);

    // GEMM1: ST[j,i] = sum_k fp[j,k] * wn[i,k]  (static K=1152)
    gemm_nt64<<<dim3(18, 18, 4), 256, 0, stream>>>(fp, wn, ST, 2304, 2304, K1, 0,
        nullptr, K1, (long)2304 * K1, (long)2304 * K1, (long)2304 * 2304);

    // fused double-diag + softmax + compaction (FT1 eliminated)
    fuse_softmax<<<dim3(LBF, 4), 256, 0, stream>>>(ST, pos, attTc);

    // GEMM2 transposed output, R4 block-order: x sweeps Wtc (A), y pins attTc (B)
    gemm_nt64<<<dim3(16, 18, 4), 256, 0, stream>>>(Wtc, attTc, MT, 2048, 2304, LDK2, 1,
        pos + 2303, 0, (long)2048 * LDK2, (long)2304 * LDK2, (long)2048 * 2304);

    scatter_out<<<dim3(36, 128, 4), 256, 0, stream>>>(MT, out);
}